// Round 1
// baseline (330.281 us; speedup 1.0000x reference)
//
#include <hip/hip_runtime.h>
#include <math.h>

#define BATCH 128
#define DIN   1024
#define DOUT  1024

// Numerically stable softplus: max(v,0) + log1p(exp(-|v|)).
// rho ~ N(-5,1) so the fast path is always safe, but keep the stable form.
__device__ __forceinline__ float softplus_f(float v) {
    return fmaxf(v, 0.0f) + log1pf(__expf(-fabsf(v)));
}

// One 64-lane wave per output element (b,o).
// Wave id -> o-major mapping: consecutive waves share the (mu,rho) row
// (stays L2-hot across the 128 batch elements) and x fits entirely in each
// XCD's 4 MiB L2, so the only real HBM stream is eps_w (512 MB, read once).
__global__ __launch_bounds__(256) void bayes_linear_kernel(
    const float* __restrict__ x,
    const float* __restrict__ wmu,
    const float* __restrict__ wrho,
    const float* __restrict__ bmu,
    const float* __restrict__ brho,
    const float* __restrict__ epsw,
    const float* __restrict__ epsb,
    float* __restrict__ out)
{
    const int wid  = (blockIdx.x << 2) + (threadIdx.x >> 6); // global wave id
    const int lane = threadIdx.x & 63;
    const int o = wid >> 7;          // 0..1023  (slow: mu/rho row reuse)
    const int b = wid & 127;         // 0..127   (fast: sweeps batch)
    const int row = b * DOUT + o;    // index into (B,OUT) tensors

    const float4* __restrict__ x4   = reinterpret_cast<const float4*>(x    + (size_t)b * DIN);
    const float4* __restrict__ mu4  = reinterpret_cast<const float4*>(wmu  + (size_t)o * DIN);
    const float4* __restrict__ rho4 = reinterpret_cast<const float4*>(wrho + (size_t)o * DIN);
    const float4* __restrict__ e4   = reinterpret_cast<const float4*>(epsw + (size_t)row * DIN);

    float acc = 0.0f;
    // 1024 elements / 64 lanes = 16 per lane = 4 x float4 (16 B/lane/iter,
    // fully coalesced: wave reads 1 KiB contiguous per instruction).
    #pragma unroll
    for (int k = 0; k < 4; ++k) {
        const int idx = lane + (k << 6);
        const float4 xe = x4[idx];
        const float4 me = mu4[idx];
        const float4 re = rho4[idx];
        const float4 ee = e4[idx];
        acc += xe.x * fmaf(softplus_f(re.x), ee.x, me.x);
        acc += xe.y * fmaf(softplus_f(re.y), ee.y, me.y);
        acc += xe.z * fmaf(softplus_f(re.z), ee.z, me.z);
        acc += xe.w * fmaf(softplus_f(re.w), ee.w, me.w);
    }

    // 64-lane butterfly reduction.
    #pragma unroll
    for (int off = 32; off >= 1; off >>= 1)
        acc += __shfl_xor(acc, off, 64);

    if (lane == 0) {
        const float bias = bmu[o] + softplus_f(brho[o]) * epsb[row];
        out[row] = acc + bias;
    }
}

extern "C" void kernel_launch(void* const* d_in, const int* in_sizes, int n_in,
                              void* d_out, int out_size, void* d_ws, size_t ws_size,
                              hipStream_t stream) {
    const float* x    = (const float*)d_in[0];
    const float* wmu  = (const float*)d_in[1];
    const float* wrho = (const float*)d_in[2];
    const float* bmu  = (const float*)d_in[3];
    const float* brho = (const float*)d_in[4];
    const float* epsw = (const float*)d_in[5];
    const float* epsb = (const float*)d_in[6];
    float* out = (float*)d_out;

    // One wave per (b,o): 128*1024 waves, 4 waves (256 threads) per block.
    const int n_waves = BATCH * DOUT;
    const int blocks  = n_waves / 4; // 32768
    bayes_linear_kernel<<<blocks, 256, 0, stream>>>(x, wmu, wrho, bmu, brho, epsw, epsb, out);
}

// Round 2
// 120.577 us; speedup vs baseline: 2.7392x; 2.7392x over previous
//
#include <hip/hip_runtime.h>
#include <math.h>

#define BATCH 128
#define DIN   1024
#define DOUT  1024
#define NB    8    // batch elements per wave: softplus amortization factor

// Numerically stable softplus: max(v,0) + log1p(exp(-|v|)).
__device__ __forceinline__ float softplus_f(float v) {
    return fmaxf(v, 0.0f) + log1pf(__expf(-fabsf(v)));
}

// One 64-lane wave per (o, batch-group-of-8).
// The wave computes sp = softplus(rho[o,:]) and loads mu[o,:] into registers
// ONCE (16 elems/lane), then streams NB=8 eps rows against them.
// This cuts softplus evaluations 8x vs one-wave-per-(b,o); the eps stream
// loop is then 2 FMA per element and the kernel should go memory-bound.
__global__ __launch_bounds__(256) void bayes_linear_kernel(
    const float* __restrict__ x,
    const float* __restrict__ wmu,
    const float* __restrict__ wrho,
    const float* __restrict__ bmu,
    const float* __restrict__ brho,
    const float* __restrict__ epsw,
    const float* __restrict__ epsb,
    float* __restrict__ out)
{
    const int wid  = (blockIdx.x << 2) + (threadIdx.x >> 6); // global wave id
    const int lane = threadIdx.x & 63;
    const int o  = wid >> 4;             // 0..1023: 16 consecutive waves share o
    const int b0 = (wid & 15) * NB;      // 0,8,...,120

    const float4* __restrict__ mu4  = reinterpret_cast<const float4*>(wmu  + (size_t)o * DIN);
    const float4* __restrict__ rho4 = reinterpret_cast<const float4*>(wrho + (size_t)o * DIN);

    // Per-lane slice of the o-row: 16 elements = 4 x float4.
    float sp[16], mu[16];
    #pragma unroll
    for (int k = 0; k < 4; ++k) {
        const int idx = lane + (k << 6);
        const float4 re = rho4[idx];
        const float4 me = mu4[idx];
        sp[4*k+0] = softplus_f(re.x);  mu[4*k+0] = me.x;
        sp[4*k+1] = softplus_f(re.y);  mu[4*k+1] = me.y;
        sp[4*k+2] = softplus_f(re.z);  mu[4*k+2] = me.z;
        sp[4*k+3] = softplus_f(re.w);  mu[4*k+3] = me.w;
    }

    float acc[NB];
    #pragma unroll
    for (int j = 0; j < NB; ++j) acc[j] = 0.0f;

    #pragma unroll
    for (int j = 0; j < NB; ++j) {
        const int b = b0 + j;
        const float4* __restrict__ x4 = reinterpret_cast<const float4*>(x + (size_t)b * DIN);
        const float4* __restrict__ e4 = reinterpret_cast<const float4*>(
            epsw + ((size_t)b * DOUT + (size_t)o) * DIN);
        float a = acc[j];
        #pragma unroll
        for (int k = 0; k < 4; ++k) {
            const int idx = lane + (k << 6);
            const float4 xe = x4[idx];   // L2-resident (x is 512 KB total)
            const float4 ee = e4[idx];   // the one true HBM stream
            a = fmaf(xe.x, fmaf(sp[4*k+0], ee.x, mu[4*k+0]), a);
            a = fmaf(xe.y, fmaf(sp[4*k+1], ee.y, mu[4*k+1]), a);
            a = fmaf(xe.z, fmaf(sp[4*k+2], ee.z, mu[4*k+2]), a);
            a = fmaf(xe.w, fmaf(sp[4*k+3], ee.w, mu[4*k+3]), a);
        }
        acc[j] = a;
    }

    // 64-lane butterfly reduction per batch element.
    #pragma unroll
    for (int j = 0; j < NB; ++j) {
        #pragma unroll
        for (int off = 32; off >= 1; off >>= 1)
            acc[j] += __shfl_xor(acc[j], off, 64);
    }

    if (lane == 0) {
        const float bsp = softplus_f(brho[o]);   // once per wave, not per b
        const float bm  = bmu[o];
        #pragma unroll
        for (int j = 0; j < NB; ++j) {
            const int b = b0 + j;
            out[(size_t)b * DOUT + o] =
                acc[j] + fmaf(bsp, epsb[(size_t)b * DOUT + o], bm);
        }
    }
}

extern "C" void kernel_launch(void* const* d_in, const int* in_sizes, int n_in,
                              void* d_out, int out_size, void* d_ws, size_t ws_size,
                              hipStream_t stream) {
    const float* x    = (const float*)d_in[0];
    const float* wmu  = (const float*)d_in[1];
    const float* wrho = (const float*)d_in[2];
    const float* bmu  = (const float*)d_in[3];
    const float* brho = (const float*)d_in[4];
    const float* epsw = (const float*)d_in[5];
    const float* epsb = (const float*)d_in[6];
    float* out = (float*)d_out;

    // waves = DOUT * (BATCH/NB) = 1024 * 16 = 16384; 4 waves per 256-thread block.
    const int n_waves = DOUT * (BATCH / NB);
    const int blocks  = n_waves / 4; // 4096
    bayes_linear_kernel<<<blocks, 256, 0, stream>>>(x, wmu, wrho, bmu, brho, epsw, epsb, out);
}